// Round 1
// 568.566 us; speedup vs baseline: 1.0483x; 1.0483x over previous
//
#include <hip/hip_runtime.h>

// B=8, S=2048, D=1024, U=1024, fp32 in/out, bf16-grade tolerance.
// Pipeline (bf16 MFMA TN GEMMs):
//   WqmT = metricT @ WqB            (metric folded into Wq)   [128^2 kernel]
//   Qb   = X1b @ WqmT + bqm  -> d_out[0:33.5MB]   [256^2 8-wave phase kernel]
//   Kb   = X2b @ WkT  + bk   -> d_out[33.5:67MB]
//   Vt_b = WvT @ X2b_b^T + bv  [U][S] per batch
//   Sc_b = Qb_b @ Kb_b^T  bf16, aliased over X1b+X2b (dead), causal tile skip
//   alpha = softmax(Sc/32) bf16 in place (read<=i+1, write<=roundup(i+1,256))
//   Out_b = alpha_b @ Vt_b^T -> d_out (fp32), causal K-limit, longest-first
// gemm_tn256: 256x256 tile, BK phases of 32, 512 thr (2x4 waves, 128x64/wave),
//   LDS = 4 rotating 16KB regions per operand (128KB, 1 block/CU),
//   counted vmcnt(12/8/4/0), XOR k-chunk swizzle (c = q ^ ((row>>1)&3)) applied
//   on pre-swizzled global source (gl_lds writes linearly) and on ds_read.
// Peak d_ws: 111,153,152 B.

#define Bq 8
#define Sq 2048
#define Dq 1024
#define Uq 1024

typedef __bf16 bf16;
typedef __bf16 bf16x8 __attribute__((ext_vector_type(8)));
typedef float f32x4 __attribute__((ext_vector_type(4)));
typedef unsigned short u16;
typedef unsigned int u32;

__device__ __forceinline__ u16 f2bf(float f) {
  u32 u = __builtin_bit_cast(u32, f);
  u32 r = u + 0x7fffu + ((u >> 16) & 1u);
  return (u16)(r >> 16);
}
__device__ __forceinline__ float bf2f(u32 h) {
  return __builtin_bit_cast(float, h << 16);
}

__device__ __forceinline__ void gl_lds16(const void* g, void* l) {
  __builtin_amdgcn_global_load_lds(
      (const __attribute__((address_space(1))) u32*)g,
      (__attribute__((address_space(3))) u32*)l, 16, 0, 0);
}

// ---------------- converts ----------------

__global__ __launch_bounds__(256) void cvt_x(const float* __restrict__ x1,
                                             const float* __restrict__ x2,
                                             u16* __restrict__ o1,
                                             u16* __restrict__ o2, int n4) {
  int idx = blockIdx.x * 256 + threadIdx.x;
  if (idx >= n4) return;
  const float* in = blockIdx.y ? x2 : x1;
  u16* out = blockIdx.y ? o2 : o1;
  float4 v = ((const float4*)in)[idx];
  ushort4 o;
  o.x = f2bf(v.x); o.y = f2bf(v.y); o.z = f2bf(v.z); o.w = f2bf(v.w);
  ((ushort4*)out)[idx] = o;
}

__global__ __launch_bounds__(256) void cvt_bf16(const float* __restrict__ in,
                                                u16* __restrict__ out, int n4) {
  int idx = blockIdx.x * 256 + threadIdx.x;
  if (idx >= n4) return;
  float4 v = ((const float4*)in)[idx];
  ushort4 o;
  o.x = f2bf(v.x); o.y = f2bf(v.y); o.z = f2bf(v.z); o.w = f2bf(v.w);
  ((ushort4*)out)[idx] = o;
}

// out[x][y] = bf16(in[y][x]), 1024x1024; z picks among 3 (src,dst) pairs
__global__ __launch_bounds__(256) void transpose_cvt3(
    const float* __restrict__ s0, u16* __restrict__ d0,
    const float* __restrict__ s1, u16* __restrict__ d1,
    const float* __restrict__ s2, u16* __restrict__ d2) {
  __shared__ float tile[32][33];
  const float* in = (blockIdx.z == 0) ? s0 : (blockIdx.z == 1) ? s1 : s2;
  u16* out = (blockIdx.z == 0) ? d0 : (blockIdx.z == 1) ? d1 : d2;
  const int N = 1024;
  int tx = threadIdx.x & 31, ty = threadIdx.x >> 5;  // 32 x 8
  int x0 = blockIdx.x * 32, y0 = blockIdx.y * 32;
#pragma unroll
  for (int r = 0; r < 32; r += 8)
    tile[ty + r][tx] = in[(size_t)(y0 + ty + r) * N + x0 + tx];
  __syncthreads();
#pragma unroll
  for (int r = 0; r < 32; r += 8)
    out[(size_t)(x0 + ty + r) * N + y0 + tx] = f2bf(tile[tx][ty + r]);
}

__global__ __launch_bounds__(256) void bqm_kernel(const float* __restrict__ bq,
                                                  const float* __restrict__ metric,
                                                  float* __restrict__ bqm) {
  int v = blockIdx.x * 256 + threadIdx.x;
  float s = 0.f;
  for (int u = 0; u < Uq; ++u) s += bq[u] * metric[(size_t)u * Uq + v];
  bqm[v] = s;
}

__global__ __launch_bounds__(256) void fill_zero(float4* __restrict__ p, int n4) {
  int i = blockIdx.x * 256 + threadIdx.x;
  if (i < n4) p[i] = float4{0.f, 0.f, 0.f, 0.f};
}

// ---------------- TN bf16 MFMA GEMM, 128^2 3-buffer (kept for small WqmT) ----
#define BM 128
#define BN 128
#define BK 32

template <int OUT_BF16, int BIAS>
__global__ __launch_bounds__(256) void gemm_tn(
    const bf16* __restrict__ A, const bf16* __restrict__ B, void* __restrict__ Cv,
    const float* __restrict__ bias, int lda, int ldb, int ldc,
    long long sA, long long sB, long long sC, int K,
    int causal_skip, int causal_klimit) {
  __shared__ __align__(16) bf16 lA[3][BM * BK];
  __shared__ __align__(16) bf16 lB[3][BN * BK];
  int bx = causal_klimit ? (gridDim.x - 1 - blockIdx.x) : blockIdx.x;
  int m0 = bx * BM, n0 = blockIdx.y * BN;
  if (causal_skip && n0 > m0 + BM - 1) return;
  long long b = blockIdx.z;
  A += b * sA;
  B += b * sB;
  int t = threadIdx.x;
  int w = t >> 6, l = t & 63;
  int wr = (w >> 1) * 64, wc = (w & 1) * 64;
  int Kend = causal_klimit ? min(K, m0 + BM) : K;
  int nk = Kend / BK;

  f32x4 acc[4][4] = {};
  int rowA = t >> 2, kc = (t & 3) * 8;
  int lm = l & 15, q = l >> 4;

  const bf16* gA = A + (long long)(m0 + rowA) * lda + kc;
  const bf16* gB = B + (long long)(n0 + rowA) * ldb + kc;
  long long a64 = (long long)64 * lda, b64 = (long long)64 * ldb;

  auto stage = [&](int kt, int buf) {
    int k0 = kt * BK;
    char* dA = (char*)lA[buf] + w * 1024;
    char* dB = (char*)lB[buf] + w * 1024;
    gl_lds16(gA + k0, dA);
    gl_lds16(gA + k0 + a64, dA + 4096);
    gl_lds16(gB + k0, dB);
    gl_lds16(gB + k0 + b64, dB + 4096);
  };

  stage(0, 0);
  stage(1, 1);
  int cur = 0;
  for (int kt = 0; kt < nk; ++kt) {
    if (kt + 2 < nk) {
      int pb = cur + 2;
      if (pb >= 3) pb -= 3;
      stage(kt + 2, pb);
      asm volatile("s_waitcnt vmcnt(8)\n\ts_barrier" ::: "memory");
    } else if (kt + 1 < nk) {
      asm volatile("s_waitcnt vmcnt(4)\n\ts_barrier" ::: "memory");
    } else {
      asm volatile("s_waitcnt vmcnt(0)\n\ts_barrier" ::: "memory");
    }
    bf16x8 af[4], bfr[4];
#pragma unroll
    for (int i = 0; i < 4; ++i)
      af[i] = *(const bf16x8*)&lA[cur][(wr + i * 16 + lm) * BK + q * 8];
#pragma unroll
    for (int i = 0; i < 4; ++i)
      bfr[i] = *(const bf16x8*)&lB[cur][(wc + i * 16 + lm) * BK + q * 8];
#pragma unroll
    for (int i = 0; i < 4; ++i)
#pragma unroll
      for (int j = 0; j < 4; ++j)
        acc[i][j] = __builtin_amdgcn_mfma_f32_16x16x32_bf16(af[i], bfr[j], acc[i][j], 0, 0, 0);
    asm volatile("s_barrier" ::: "memory");
    cur = (cur == 2) ? 0 : cur + 1;
  }

  char* Cb = (char*)Cv + (OUT_BF16 ? b * sC * 2 : b * sC * 4);
#pragma unroll
  for (int i = 0; i < 4; ++i) {
#pragma unroll
    for (int j = 0; j < 4; ++j) {
      int col = n0 + wc + j * 16 + lm;
      float bc = (BIAS == 1) ? bias[col] : 0.f;
#pragma unroll
      for (int r = 0; r < 4; ++r) {
        int row = m0 + wr + i * 16 + q * 4 + r;
        float v = acc[i][j][r] + bc;
        if (BIAS == 2) v += bias[row];
        size_t idx = (size_t)row * ldc + col;
        if (OUT_BF16)
          ((u16*)Cb)[idx] = f2bf(v);
        else
          ((float*)Cb)[idx] = v;
      }
    }
  }
}

// ---------------- TN bf16 MFMA GEMM, 256^2 8-wave phase pipeline -------------
// 512 threads = 8 waves (2 M x 4 N), per-wave output 128x64 (acc[8][4]).
// K consumed in 32-wide phases. LDS: 4 rotating regions per operand,
// region r(p) = p&3, each [256][32] bf16 (16KB). Stage for phase p+4 is issued
// only after the barrier closing phase p's reads (r(p+4)==r(p)).
// Steady state: 3 stages x 4 loads in flight -> vmcnt(12), never 0 mid-loop.
// Swizzle: LDS row of 32 bf16 = 4 chunks of 16B; chunk c at row holds global
// k-chunk c ^ ((row>>1)&3). Reads use c = q ^ ((lm>>1)&3) -> quarter-wave
// lanes hit all 8 four-bank groups (2-way, free).

template <int OUT_BF16, int BIAS>
__global__ __launch_bounds__(512, 2) void gemm_tn256(
    const bf16* __restrict__ A, const bf16* __restrict__ B, void* __restrict__ Cv,
    const float* __restrict__ bias, int lda, int ldb, int ldc,
    long long sA, long long sB, long long sC, int K,
    int causal_skip, int causal_klimit) {
  __shared__ __align__(16) bf16 lA[4][256 * 32];  // 64 KB
  __shared__ __align__(16) bf16 lB[4][256 * 32];  // 64 KB
  int bx = causal_klimit ? (gridDim.x - 1 - blockIdx.x) : blockIdx.x;
  int m0 = bx * 256, n0 = blockIdx.y * 256;
  if (causal_skip && n0 > m0 + 255) return;
  long long b = blockIdx.z;
  A += b * sA;
  B += b * sB;
  int t = threadIdx.x;
  int w = t >> 6, l = t & 63;
  int wr = w >> 2, wc = w & 3;       // wave tile: rows wr*128.., cols wc*64..
  int lm = l & 15, q = l >> 4;
  int cq = q ^ ((lm >> 1) & 3);      // swizzled k-chunk for fragment reads

  int Kend = causal_klimit ? min(K, m0 + 256) : K;
  int NP = Kend >> 5;  // number of 32-k phases (multiple of 8 in all our uses)

  // ---- staging precompute: thread covers (row=t>>2 [+128], chunk=t&3) ----
  int r0 = t >> 2;                   // 0..127
  int c0 = t & 3;
  int q0 = c0 ^ ((r0 >> 1) & 3);     // same for row r0+128 (128>>1 ≡ 0 mod 4)
  const bf16* gA0 = A + (long long)(m0 + r0) * lda + q0 * 8;
  const bf16* gA1 = gA0 + (long long)128 * lda;
  const bf16* gB0 = B + (long long)(n0 + r0) * ldb + q0 * 8;
  const bf16* gB1 = gB0 + (long long)128 * ldb;
  char* dA = (char*)&lA[0][0] + w * 1024;  // wave-uniform LDS dest
  char* dB = (char*)&lB[0][0] + w * 1024;

  auto stage = [&](int ph) {
    int reg_ = ph & 3;
    int k0 = ph << 5;
    char* da = dA + reg_ * 16384;
    char* db = dB + reg_ * 16384;
    gl_lds16(gA0 + k0, da);
    gl_lds16(gA1 + k0, da + 8192);
    gl_lds16(gB0 + k0, db);
    gl_lds16(gB1 + k0, db + 8192);
  };

  stage(0); stage(1); stage(2); stage(3);

  f32x4 acc[8][4] = {};
  const bf16* pAl = &lA[0][0] + (wr * 128 + lm) * 32 + cq * 8;
  const bf16* pBl = &lB[0][0] + (wc * 64 + lm) * 32 + cq * 8;

  for (int p = 0; p < NP; ++p) {
    // wait for stage(p) to land; keep stages p+1..p+3 in flight
    if (p + 3 < NP)
      asm volatile("s_waitcnt vmcnt(12)\n\ts_barrier" ::: "memory");
    else if (p + 2 < NP)
      asm volatile("s_waitcnt vmcnt(8)\n\ts_barrier" ::: "memory");
    else if (p + 1 < NP)
      asm volatile("s_waitcnt vmcnt(4)\n\ts_barrier" ::: "memory");
    else
      asm volatile("s_waitcnt vmcnt(0)\n\ts_barrier" ::: "memory");

    int reg_ = p & 3;
    const bf16* pa = pAl + reg_ * 8192;
    const bf16* pb = pBl + reg_ * 8192;
    bf16x8 af[8], bfr[4];
#pragma unroll
    for (int j = 0; j < 4; ++j) bfr[j] = *(const bf16x8*)(pb + j * 512);
#pragma unroll
    for (int i = 0; i < 8; ++i) af[i] = *(const bf16x8*)(pa + i * 512);
    __builtin_amdgcn_s_setprio(1);
#pragma unroll
    for (int i = 0; i < 8; ++i)
#pragma unroll
      for (int j = 0; j < 4; ++j)
        acc[i][j] = __builtin_amdgcn_mfma_f32_16x16x32_bf16(af[i], bfr[j], acc[i][j], 0, 0, 0);
    __builtin_amdgcn_s_setprio(0);
    // all waves done reading region r(p) before its overwrite is issued
    asm volatile("s_barrier" ::: "memory");
    if (p + 4 < NP) stage(p + 4);
  }

  // epilogue: row = m0 + wr*128 + i*16 + q*4 + r ; col = n0 + wc*64 + j*16 + lm
  char* Cb = (char*)Cv + (OUT_BF16 ? b * sC * 2 : b * sC * 4);
#pragma unroll
  for (int i = 0; i < 8; ++i) {
#pragma unroll
    for (int j = 0; j < 4; ++j) {
      int col = n0 + wc * 64 + j * 16 + lm;
      float bc = (BIAS == 1) ? bias[col] : 0.f;
#pragma unroll
      for (int r = 0; r < 4; ++r) {
        int row = m0 + wr * 128 + i * 16 + q * 4 + r;
        float v = acc[i][j][r] + bc;
        if (BIAS == 2) v += bias[row];
        size_t idxc = (size_t)row * ldc + col;
        if (OUT_BF16)
          ((u16*)Cb)[idxc] = f2bf(v);
        else
          ((float*)Cb)[idxc] = v;
      }
    }
  }
}

// ---------------- causal softmax (bf16 in place) ----------------
// Reads only j <= i; writes zeros up to the 256-aligned limit the Out GEMM
// reads (Kend = roundup(i+1,256)); leaves garbage beyond (never read).
__global__ __launch_bounds__(256) void softmax_causal(u16* __restrict__ sc) {
  __shared__ __align__(16) float sm[Sq];
  __shared__ float red[8];
  int gr = blockIdx.x;
  int i = gr & (Sq - 1);
  u16* rowp = sc + (size_t)gr * Sq;
  int t = threadIdx.x;
  int nv = i + 1;
  int wlim = (i & ~255) + 256;
  int j0 = t * 8;
  if (j0 < nv) {
    uint4 pk = ((const uint4*)rowp)[t];  // 8 bf16
    float4 lo, hi;
    lo.x = bf2f(pk.x & 0xffffu); lo.y = bf2f(pk.x >> 16);
    lo.z = bf2f(pk.y & 0xffffu); lo.w = bf2f(pk.y >> 16);
    hi.x = bf2f(pk.z & 0xffffu); hi.y = bf2f(pk.z >> 16);
    hi.z = bf2f(pk.w & 0xffffu); hi.w = bf2f(pk.w >> 16);
    ((float4*)sm)[2 * t] = lo;
    ((float4*)sm)[2 * t + 1] = hi;
  }
  __syncthreads();
  const float scl = 0.03125f;  // 1/sqrt(U) = 1/32
  float m = -1e30f;
  for (int j = t; j < nv; j += 256) m = fmaxf(m, sm[j]);
#pragma unroll
  for (int o = 32; o; o >>= 1) m = fmaxf(m, __shfl_xor(m, o));
  if ((t & 63) == 0) red[t >> 6] = m;
  __syncthreads();
  m = fmaxf(fmaxf(red[0], red[1]), fmaxf(red[2], red[3])) * scl;
  float sum = 0.f;
  for (int j = t; j < nv; j += 256) sum += __expf(sm[j] * scl - m);
#pragma unroll
  for (int o = 32; o; o >>= 1) sum += __shfl_xor(sum, o);
  if ((t & 63) == 0) red[4 + (t >> 6)] = sum;
  __syncthreads();
  float rinv = 1.0f / (red[4] + red[5] + red[6] + red[7]);
  if (j0 < wlim) {
    u16 ov[8];
#pragma unroll
    for (int k = 0; k < 8; ++k)
      ov[k] = (j0 + k < nv) ? f2bf(__expf(sm[j0 + k] * scl - m) * rinv) : (u16)0;
    uint4 po;
    po.x = (u32)ov[0] | ((u32)ov[1] << 16);
    po.y = (u32)ov[2] | ((u32)ov[3] << 16);
    po.z = (u32)ov[4] | ((u32)ov[5] << 16);
    po.w = (u32)ov[6] | ((u32)ov[7] << 16);
    ((uint4*)rowp)[t] = po;
  }
}

// ---------------- launch ----------------

extern "C" void kernel_launch(void* const* d_in, const int* in_sizes, int n_in,
                              void* d_out, int out_size, void* d_ws, size_t ws_size,
                              hipStream_t stream) {
  const float* X1 = (const float*)d_in[0];
  const float* X2 = (const float*)d_in[1];
  const float* Wq = (const float*)d_in[2];
  const float* bq = (const float*)d_in[3];
  const float* Wk = (const float*)d_in[4];
  const float* bk = (const float*)d_in[5];
  const float* Wv = (const float*)d_in[6];
  const float* bv = (const float*)d_in[7];
  const float* metric = (const float*)d_in[8];
  float* out = (float*)d_out;

  const size_t XB = (size_t)Bq * Sq * Dq * 2;  // 33,554,432 B
  const size_t WB = (size_t)Dq * Uq * 2;       // 2,097,152 B
  const size_t NEED = 3 * XB + 5 * WB + 4096;  // 111,153,152 B

  if (ws_size < NEED) {
    fill_zero<<<(out_size / 4 + 255) / 256, 256, 0, stream>>>((float4*)d_out, out_size / 4);
    return;
  }

  char* ws = (char*)d_ws;
  bf16* X1b = (bf16*)(ws);
  bf16* X2b = (bf16*)(ws + XB);
  bf16* Vt = (bf16*)(ws + 2 * XB);
  bf16* WqB = (bf16*)(ws + 3 * XB);
  bf16* metT = (bf16*)(ws + 3 * XB + WB);
  bf16* WkT = (bf16*)(ws + 3 * XB + 2 * WB);
  bf16* WvT = (bf16*)(ws + 3 * XB + 3 * WB);
  bf16* WqmT = (bf16*)(ws + 3 * XB + 4 * WB);
  float* bqm = (float*)(ws + 3 * XB + 5 * WB);
  u16* Sc = (u16*)ws;  // bf16 scores alias X1b+X2b (dead by then)
  bf16* Qb = (bf16*)d_out;                          // scratch in d_out
  bf16* Kb = (bf16*)d_out + (size_t)Bq * Sq * Uq;   // second half of d_out

  // converts
  int nx4 = Bq * Sq * Dq / 4;
  cvt_x<<<dim3((nx4 + 255) / 256, 2), 256, 0, stream>>>(X1, X2, (u16*)X1b, (u16*)X2b, nx4);
  cvt_bf16<<<(Dq * Uq / 4 + 255) / 256, 256, 0, stream>>>(Wq, (u16*)WqB, Dq * Uq / 4);
  transpose_cvt3<<<dim3(32, 32, 3), 256, 0, stream>>>(
      metric, (u16*)metT, Wk, (u16*)WkT, Wv, (u16*)WvT);
  bqm_kernel<<<Uq / 256, 256, 0, stream>>>(bq, metric, bqm);

  // WqmT[v][d] = sum_u metT[v][u] * WqB[d][u]   (small: keep 128^2 kernel)
  gemm_tn<1, 0><<<dim3(Uq / BM, Dq / BN, 1), 256, 0, stream>>>(
      metT, WqB, WqmT, nullptr, Uq, Uq, Dq, 0, 0, 0, Uq, 0, 0);

  const int MQ = Bq * Sq;  // 16384
  // Qb = X1b @ WqmT^T + bqm   -> d_out scratch
  gemm_tn256<1, 1><<<dim3(MQ / 256, Uq / 256, 1), 512, 0, stream>>>(
      X1b, WqmT, Qb, bqm, Dq, Dq, Uq, 0, 0, 0, Dq, 0, 0);
  // Kb = X2b @ WkT + bk       -> d_out scratch
  gemm_tn256<1, 1><<<dim3(MQ / 256, Uq / 256, 1), 512, 0, stream>>>(
      X2b, WkT, Kb, bk, Dq, Dq, Uq, 0, 0, 0, Dq, 0, 0);
  // Vt[b][u][j] = sum_d WvT[u][d] * X2b[b][j][d] + bv[u]
  gemm_tn256<1, 2><<<dim3(Uq / 256, Sq / 256, Bq), 512, 0, stream>>>(
      WvT, X2b, Vt, bv, Dq, Dq, Sq, 0, (long long)Sq * Dq, (long long)Uq * Sq, Dq, 0, 0);

  // Sc[b][i][j] = Qb_b[i] . Kb_b[j]  (bf16 out, skip fully-masked 256-tiles)
  gemm_tn256<1, 0><<<dim3(Sq / 256, Sq / 256, Bq), 512, 0, stream>>>(
      Qb, Kb, Sc, nullptr, Uq, Uq, Sq, (long long)Sq * Uq, (long long)Sq * Uq,
      (long long)Sq * Sq, Uq, 1, 0);

  softmax_causal<<<Bq * Sq, 256, 0, stream>>>(Sc);

  // Out[b][i][u] = sum_j alpha[b][i][j] * Vt[b][u][j]  (causal K-limit, longest-first)
  gemm_tn256<0, 0><<<dim3(Sq / 256, Uq / 256, Bq), 512, 0, stream>>>(
      (const bf16*)Sc, Vt, out, nullptr, Sq, Sq, Uq, (long long)Sq * Sq,
      (long long)Uq * Sq, (long long)Sq * Uq, Sq, 0, 1);

  (void)in_sizes; (void)n_in; (void)ws_size;
}

// Round 2
// 524.491 us; speedup vs baseline: 1.1364x; 1.0840x over previous
//
#include <hip/hip_runtime.h>

// B=8, S=2048, D=1024, U=1024, fp32 in/out, bf16-grade tolerance.
// Pipeline (bf16 MFMA TN GEMMs):
//   WqmT = metricT @ WqB            (metric folded into Wq)   [128^2 kernel]
//   Qb   = X1b @ WqmT + bqm  -> d_out[0:33.5MB]   [256^2 8-wave phase kernel]
//   Kb   = X2b @ WkT  + bk   -> d_out[33.5:67MB]
//   Vt_b = WvT @ X2b_b^T + bv  [U][S] per batch
//   Sc_b = Qb_b @ Kb_b^T  bf16, aliased over X1b+X2b (dead), causal tile skip
//   alpha = softmax(Sc/32) bf16 in place (read<=i+1, write<=roundup(i+1,256))
//   Out_b = alpha_b @ Vt_b^T -> d_out (fp32), causal K-limit, longest-first
// gemm_tn256 (R2 schedule): 256x256 tile, 512 thr (2x4 waves, 128x64/wave),
//   K phases of 32; LDS = 4 rotating 16KB regions/operand (128KB, 1 blk/CU).
//   Per phase, ONE barrier: stage(p+3)->r(p-1); issue aHi reads; MFMA-lo
//   (covers aHi latency); issue next-phase aLo+B reads; MFMA-hi (covers);
//   lgkmcnt(0)+vmcnt(4)+barrier. Fragment regs double-buffered via statically
//   named sets (unroll-by-2). Region ledger:
//     - reads of r(q) all lgkm(0)'d before the barrier preceding stage into r(q)
//     - stage(q) vmcnt-verified+barrier'd one body before its first read
//   XOR k-chunk swizzle (c = q ^ ((row>>1)&3)) on pre-swizzled global source
//   (gl_lds writes linearly) and on ds_read -> 0 bank conflicts (verified R1).
// Peak d_ws: 111,153,152 B.

#define Bq 8
#define Sq 2048
#define Dq 1024
#define Uq 1024

typedef __bf16 bf16;
typedef __bf16 bf16x8 __attribute__((ext_vector_type(8)));
typedef float f32x4 __attribute__((ext_vector_type(4)));
typedef unsigned short u16;
typedef unsigned int u32;

__device__ __forceinline__ u16 f2bf(float f) {
  u32 u = __builtin_bit_cast(u32, f);
  u32 r = u + 0x7fffu + ((u >> 16) & 1u);
  return (u16)(r >> 16);
}
__device__ __forceinline__ float bf2f(u32 h) {
  return __builtin_bit_cast(float, h << 16);
}

__device__ __forceinline__ void gl_lds16(const void* g, void* l) {
  __builtin_amdgcn_global_load_lds(
      (const __attribute__((address_space(1))) u32*)g,
      (__attribute__((address_space(3))) u32*)l, 16, 0, 0);
}

// ---------------- converts ----------------

__global__ __launch_bounds__(256) void cvt_x(const float* __restrict__ x1,
                                             const float* __restrict__ x2,
                                             u16* __restrict__ o1,
                                             u16* __restrict__ o2, int n4) {
  int idx = blockIdx.x * 256 + threadIdx.x;
  if (idx >= n4) return;
  const float* in = blockIdx.y ? x2 : x1;
  u16* out = blockIdx.y ? o2 : o1;
  float4 v = ((const float4*)in)[idx];
  ushort4 o;
  o.x = f2bf(v.x); o.y = f2bf(v.y); o.z = f2bf(v.z); o.w = f2bf(v.w);
  ((ushort4*)out)[idx] = o;
}

__global__ __launch_bounds__(256) void cvt_bf16(const float* __restrict__ in,
                                                u16* __restrict__ out, int n4) {
  int idx = blockIdx.x * 256 + threadIdx.x;
  if (idx >= n4) return;
  float4 v = ((const float4*)in)[idx];
  ushort4 o;
  o.x = f2bf(v.x); o.y = f2bf(v.y); o.z = f2bf(v.z); o.w = f2bf(v.w);
  ((ushort4*)out)[idx] = o;
}

// out[x][y] = bf16(in[y][x]), 1024x1024; z picks among 3 (src,dst) pairs
__global__ __launch_bounds__(256) void transpose_cvt3(
    const float* __restrict__ s0, u16* __restrict__ d0,
    const float* __restrict__ s1, u16* __restrict__ d1,
    const float* __restrict__ s2, u16* __restrict__ d2) {
  __shared__ float tile[32][33];
  const float* in = (blockIdx.z == 0) ? s0 : (blockIdx.z == 1) ? s1 : s2;
  u16* out = (blockIdx.z == 0) ? d0 : (blockIdx.z == 1) ? d1 : d2;
  const int N = 1024;
  int tx = threadIdx.x & 31, ty = threadIdx.x >> 5;  // 32 x 8
  int x0 = blockIdx.x * 32, y0 = blockIdx.y * 32;
#pragma unroll
  for (int r = 0; r < 32; r += 8)
    tile[ty + r][tx] = in[(size_t)(y0 + ty + r) * N + x0 + tx];
  __syncthreads();
#pragma unroll
  for (int r = 0; r < 32; r += 8)
    out[(size_t)(x0 + ty + r) * N + y0 + tx] = f2bf(tile[tx][ty + r]);
}

__global__ __launch_bounds__(256) void bqm_kernel(const float* __restrict__ bq,
                                                  const float* __restrict__ metric,
                                                  float* __restrict__ bqm) {
  int v = blockIdx.x * 256 + threadIdx.x;
  float s = 0.f;
  for (int u = 0; u < Uq; ++u) s += bq[u] * metric[(size_t)u * Uq + v];
  bqm[v] = s;
}

__global__ __launch_bounds__(256) void fill_zero(float4* __restrict__ p, int n4) {
  int i = blockIdx.x * 256 + threadIdx.x;
  if (i < n4) p[i] = float4{0.f, 0.f, 0.f, 0.f};
}

// ---------------- TN bf16 MFMA GEMM, 128^2 3-buffer (kept for small WqmT) ----
#define BM 128
#define BN 128
#define BK 32

template <int OUT_BF16, int BIAS>
__global__ __launch_bounds__(256) void gemm_tn(
    const bf16* __restrict__ A, const bf16* __restrict__ B, void* __restrict__ Cv,
    const float* __restrict__ bias, int lda, int ldb, int ldc,
    long long sA, long long sB, long long sC, int K,
    int causal_skip, int causal_klimit) {
  __shared__ __align__(16) bf16 lA[3][BM * BK];
  __shared__ __align__(16) bf16 lB[3][BN * BK];
  int bx = causal_klimit ? (gridDim.x - 1 - blockIdx.x) : blockIdx.x;
  int m0 = bx * BM, n0 = blockIdx.y * BN;
  if (causal_skip && n0 > m0 + BM - 1) return;
  long long b = blockIdx.z;
  A += b * sA;
  B += b * sB;
  int t = threadIdx.x;
  int w = t >> 6, l = t & 63;
  int wr = (w >> 1) * 64, wc = (w & 1) * 64;
  int Kend = causal_klimit ? min(K, m0 + BM) : K;
  int nk = Kend / BK;

  f32x4 acc[4][4] = {};
  int rowA = t >> 2, kc = (t & 3) * 8;
  int lm = l & 15, q = l >> 4;

  const bf16* gA = A + (long long)(m0 + rowA) * lda + kc;
  const bf16* gB = B + (long long)(n0 + rowA) * ldb + kc;
  long long a64 = (long long)64 * lda, b64 = (long long)64 * ldb;

  auto stage = [&](int kt, int buf) {
    int k0 = kt * BK;
    char* dA = (char*)lA[buf] + w * 1024;
    char* dB = (char*)lB[buf] + w * 1024;
    gl_lds16(gA + k0, dA);
    gl_lds16(gA + k0 + a64, dA + 4096);
    gl_lds16(gB + k0, dB);
    gl_lds16(gB + k0 + b64, dB + 4096);
  };

  stage(0, 0);
  stage(1, 1);
  int cur = 0;
  for (int kt = 0; kt < nk; ++kt) {
    if (kt + 2 < nk) {
      int pb = cur + 2;
      if (pb >= 3) pb -= 3;
      stage(kt + 2, pb);
      asm volatile("s_waitcnt vmcnt(8)\n\ts_barrier" ::: "memory");
    } else if (kt + 1 < nk) {
      asm volatile("s_waitcnt vmcnt(4)\n\ts_barrier" ::: "memory");
    } else {
      asm volatile("s_waitcnt vmcnt(0)\n\ts_barrier" ::: "memory");
    }
    bf16x8 af[4], bfr[4];
#pragma unroll
    for (int i = 0; i < 4; ++i)
      af[i] = *(const bf16x8*)&lA[cur][(wr + i * 16 + lm) * BK + q * 8];
#pragma unroll
    for (int i = 0; i < 4; ++i)
      bfr[i] = *(const bf16x8*)&lB[cur][(wc + i * 16 + lm) * BK + q * 8];
#pragma unroll
    for (int i = 0; i < 4; ++i)
#pragma unroll
      for (int j = 0; j < 4; ++j)
        acc[i][j] = __builtin_amdgcn_mfma_f32_16x16x32_bf16(af[i], bfr[j], acc[i][j], 0, 0, 0);
    asm volatile("s_barrier" ::: "memory");
    cur = (cur == 2) ? 0 : cur + 1;
  }

  char* Cb = (char*)Cv + (OUT_BF16 ? b * sC * 2 : b * sC * 4);
#pragma unroll
  for (int i = 0; i < 4; ++i) {
#pragma unroll
    for (int j = 0; j < 4; ++j) {
      int col = n0 + wc + j * 16 + lm;
      float bc = (BIAS == 1) ? bias[col] : 0.f;
#pragma unroll
      for (int r = 0; r < 4; ++r) {
        int row = m0 + wr + i * 16 + q * 4 + r;
        float v = acc[i][j][r] + bc;
        if (BIAS == 2) v += bias[row];
        size_t idx = (size_t)row * ldc + col;
        if (OUT_BF16)
          ((u16*)Cb)[idx] = f2bf(v);
        else
          ((float*)Cb)[idx] = v;
      }
    }
  }
}

// ---------------- TN bf16 MFMA GEMM, 256^2 8-wave single-barrier pipeline ----
// See header comment. NP is always even (K multiple of 256) -> unroll-by-2
// with statically named fragment register sets (no runtime-indexed arrays).

#define GBODY(P, CLO, CB, NLO, NB)                                             \
  {                                                                            \
    const int rp_ = (P) & 3, rn_ = ((P) + 1) & 3;                              \
    if ((P) + 3 < NP) stage((P) + 3);                                          \
    const bf16* pa_ = pAl + rp_ * 8192;                                        \
    _Pragma("unroll") for (int i = 0; i < 4; ++i)                              \
        aHi[i] = *(const bf16x8*)(pa_ + (i + 4) * 512);                        \
    __builtin_amdgcn_s_setprio(1);                                             \
    _Pragma("unroll") for (int i = 0; i < 4; ++i)                              \
        _Pragma("unroll") for (int j = 0; j < 4; ++j)                          \
            acc[i][j] = __builtin_amdgcn_mfma_f32_16x16x32_bf16(               \
                CLO[i], CB[j], acc[i][j], 0, 0, 0);                            \
    __builtin_amdgcn_s_setprio(0);                                             \
    if ((P) + 1 < NP) {                                                        \
      const bf16* pa2_ = pAl + rn_ * 8192;                                     \
      const bf16* pb2_ = pBl + rn_ * 8192;                                     \
      _Pragma("unroll") for (int i = 0; i < 4; ++i)                            \
          NLO[i] = *(const bf16x8*)(pa2_ + i * 512);                           \
      _Pragma("unroll") for (int j = 0; j < 4; ++j)                            \
          NB[j] = *(const bf16x8*)(pb2_ + j * 512);                            \
    }                                                                          \
    __builtin_amdgcn_s_setprio(1);                                             \
    _Pragma("unroll") for (int i = 0; i < 4; ++i)                              \
        _Pragma("unroll") for (int j = 0; j < 4; ++j)                          \
            acc[i + 4][j] = __builtin_amdgcn_mfma_f32_16x16x32_bf16(           \
                aHi[i], CB[j], acc[i + 4][j], 0, 0, 0);                        \
    __builtin_amdgcn_s_setprio(0);                                             \
    if ((P) + 3 < NP)                                                          \
      asm volatile("s_waitcnt vmcnt(4) lgkmcnt(0)\n\ts_barrier" ::: "memory"); \
    else if ((P) + 2 < NP)                                                     \
      asm volatile("s_waitcnt vmcnt(0) lgkmcnt(0)\n\ts_barrier" ::: "memory"); \
  }

template <int OUT_BF16, int BIAS>
__global__ __launch_bounds__(512, 2) void gemm_tn256(
    const bf16* __restrict__ A, const bf16* __restrict__ B, void* __restrict__ Cv,
    const float* __restrict__ bias, int lda, int ldb, int ldc,
    long long sA, long long sB, long long sC, int K,
    int causal_skip, int causal_klimit) {
  __shared__ __align__(16) bf16 lA[4][256 * 32];  // 64 KB
  __shared__ __align__(16) bf16 lB[4][256 * 32];  // 64 KB
  int bx = causal_klimit ? (gridDim.x - 1 - blockIdx.x) : blockIdx.x;
  int m0 = bx * 256, n0 = blockIdx.y * 256;
  if (causal_skip && n0 > m0 + 255) return;
  long long b = blockIdx.z;
  A += b * sA;
  B += b * sB;
  int t = threadIdx.x;
  int w = t >> 6, l = t & 63;
  int wr = w >> 2, wc = w & 3;       // wave tile: rows wr*128.., cols wc*64..
  int lm = l & 15, q = l >> 4;
  int cq = q ^ ((lm >> 1) & 3);      // swizzled k-chunk for fragment reads

  int Kend = causal_klimit ? min(K, m0 + 256) : K;
  int NP = Kend >> 5;  // even, >= 8 for all our shapes

  // ---- staging precompute: thread covers (row=t>>2 [+128], chunk=t&3) ----
  int r0 = t >> 2;                   // 0..127
  int c0 = t & 3;
  int q0 = c0 ^ ((r0 >> 1) & 3);     // same for row r0+128 (128>>1 ≡ 0 mod 4)
  const bf16* gA0 = A + (long long)(m0 + r0) * lda + q0 * 8;
  const bf16* gA1 = gA0 + (long long)128 * lda;
  const bf16* gB0 = B + (long long)(n0 + r0) * ldb + q0 * 8;
  const bf16* gB1 = gB0 + (long long)128 * ldb;
  char* dA = (char*)&lA[0][0] + w * 1024;  // wave-uniform LDS dest
  char* dB = (char*)&lB[0][0] + w * 1024;

  auto stage = [&](int ph) {
    int reg_ = ph & 3;
    int k0 = ph << 5;
    char* da = dA + reg_ * 16384;
    char* db = dB + reg_ * 16384;
    gl_lds16(gA0 + k0, da);
    gl_lds16(gA1 + k0, da + 8192);
    gl_lds16(gB0 + k0, db);
    gl_lds16(gB1 + k0, db + 8192);
  };

  const bf16* pAl = &lA[0][0] + (wr * 128 + lm) * 32 + cq * 8;
  const bf16* pBl = &lB[0][0] + (wc * 64 + lm) * 32 + cq * 8;

  f32x4 acc[8][4] = {};
  bf16x8 aLoA[4], bFrA[4], aLoB[4], bFrB[4], aHi[4];

  // prologue: 3 stages in flight; set-A fragments for phase 0
  stage(0); stage(1); stage(2);
  asm volatile("s_waitcnt vmcnt(8)\n\ts_barrier" ::: "memory");  // stage0 visible
#pragma unroll
  for (int i = 0; i < 4; ++i) aLoA[i] = *(const bf16x8*)(pAl + i * 512);
#pragma unroll
  for (int j = 0; j < 4; ++j) bFrA[j] = *(const bf16x8*)(pBl + j * 512);
  asm volatile("s_waitcnt vmcnt(4) lgkmcnt(0)\n\ts_barrier" ::: "memory");  // stage1 visible

  for (int p = 0; p < NP; p += 2) {
    GBODY(p, aLoA, bFrA, aLoB, bFrB)
    GBODY(p + 1, aLoB, bFrB, aLoA, bFrA)
  }

  // epilogue: row = m0 + wr*128 + i*16 + q*4 + r ; col = n0 + wc*64 + j*16 + lm
  char* Cb = (char*)Cv + (OUT_BF16 ? b * sC * 2 : b * sC * 4);
#pragma unroll
  for (int i = 0; i < 8; ++i) {
#pragma unroll
    for (int j = 0; j < 4; ++j) {
      int col = n0 + wc * 64 + j * 16 + lm;
      float bc = (BIAS == 1) ? bias[col] : 0.f;
#pragma unroll
      for (int r = 0; r < 4; ++r) {
        int row = m0 + wr * 128 + i * 16 + q * 4 + r;
        float v = acc[i][j][r] + bc;
        if (BIAS == 2) v += bias[row];
        size_t idxc = (size_t)row * ldc + col;
        if (OUT_BF16)
          ((u16*)Cb)[idxc] = f2bf(v);
        else
          ((float*)Cb)[idxc] = v;
      }
    }
  }
}

// ---------------- causal softmax (bf16 in place) ----------------
// Reads only j <= i; writes zeros up to the 256-aligned limit the Out GEMM
// reads (Kend = roundup(i+1,256)); leaves garbage beyond (never read).
__global__ __launch_bounds__(256) void softmax_causal(u16* __restrict__ sc) {
  __shared__ __align__(16) float sm[Sq];
  __shared__ float red[8];
  int gr = blockIdx.x;
  int i = gr & (Sq - 1);
  u16* rowp = sc + (size_t)gr * Sq;
  int t = threadIdx.x;
  int nv = i + 1;
  int wlim = (i & ~255) + 256;
  int j0 = t * 8;
  if (j0 < nv) {
    uint4 pk = ((const uint4*)rowp)[t];  // 8 bf16
    float4 lo, hi;
    lo.x = bf2f(pk.x & 0xffffu); lo.y = bf2f(pk.x >> 16);
    lo.z = bf2f(pk.y & 0xffffu); lo.w = bf2f(pk.y >> 16);
    hi.x = bf2f(pk.z & 0xffffu); hi.y = bf2f(pk.z >> 16);
    hi.z = bf2f(pk.w & 0xffffu); hi.w = bf2f(pk.w >> 16);
    ((float4*)sm)[2 * t] = lo;
    ((float4*)sm)[2 * t + 1] = hi;
  }
  __syncthreads();
  const float scl = 0.03125f;  // 1/sqrt(U) = 1/32
  float m = -1e30f;
  for (int j = t; j < nv; j += 256) m = fmaxf(m, sm[j]);
#pragma unroll
  for (int o = 32; o; o >>= 1) m = fmaxf(m, __shfl_xor(m, o));
  if ((t & 63) == 0) red[t >> 6] = m;
  __syncthreads();
  m = fmaxf(fmaxf(red[0], red[1]), fmaxf(red[2], red[3])) * scl;
  float sum = 0.f;
  for (int j = t; j < nv; j += 256) sum += __expf(sm[j] * scl - m);
#pragma unroll
  for (int o = 32; o; o >>= 1) sum += __shfl_xor(sum, o);
  if ((t & 63) == 0) red[4 + (t >> 6)] = sum;
  __syncthreads();
  float rinv = 1.0f / (red[4] + red[5] + red[6] + red[7]);
  if (j0 < wlim) {
    u16 ov[8];
#pragma unroll
    for (int k = 0; k < 8; ++k)
      ov[k] = (j0 + k < nv) ? f2bf(__expf(sm[j0 + k] * scl - m) * rinv) : (u16)0;
    uint4 po;
    po.x = (u32)ov[0] | ((u32)ov[1] << 16);
    po.y = (u32)ov[2] | ((u32)ov[3] << 16);
    po.z = (u32)ov[4] | ((u32)ov[5] << 16);
    po.w = (u32)ov[6] | ((u32)ov[7] << 16);
    ((uint4*)rowp)[t] = po;
  }
}

// ---------------- launch ----------------

extern "C" void kernel_launch(void* const* d_in, const int* in_sizes, int n_in,
                              void* d_out, int out_size, void* d_ws, size_t ws_size,
                              hipStream_t stream) {
  const float* X1 = (const float*)d_in[0];
  const float* X2 = (const float*)d_in[1];
  const float* Wq = (const float*)d_in[2];
  const float* bq = (const float*)d_in[3];
  const float* Wk = (const float*)d_in[4];
  const float* bk = (const float*)d_in[5];
  const float* Wv = (const float*)d_in[6];
  const float* bv = (const float*)d_in[7];
  const float* metric = (const float*)d_in[8];
  float* out = (float*)d_out;

  const size_t XB = (size_t)Bq * Sq * Dq * 2;  // 33,554,432 B
  const size_t WB = (size_t)Dq * Uq * 2;       // 2,097,152 B
  const size_t NEED = 3 * XB + 5 * WB + 4096;  // 111,153,152 B

  if (ws_size < NEED) {
    fill_zero<<<(out_size / 4 + 255) / 256, 256, 0, stream>>>((float4*)d_out, out_size / 4);
    return;
  }

  char* ws = (char*)d_ws;
  bf16* X1b = (bf16*)(ws);
  bf16* X2b = (bf16*)(ws + XB);
  bf16* Vt = (bf16*)(ws + 2 * XB);
  bf16* WqB = (bf16*)(ws + 3 * XB);
  bf16* metT = (bf16*)(ws + 3 * XB + WB);
  bf16* WkT = (bf16*)(ws + 3 * XB + 2 * WB);
  bf16* WvT = (bf16*)(ws + 3 * XB + 3 * WB);
  bf16* WqmT = (bf16*)(ws + 3 * XB + 4 * WB);
  float* bqm = (float*)(ws + 3 * XB + 5 * WB);
  u16* Sc = (u16*)ws;  // bf16 scores alias X1b+X2b (dead by then)
  bf16* Qb = (bf16*)d_out;                          // scratch in d_out
  bf16* Kb = (bf16*)d_out + (size_t)Bq * Sq * Uq;   // second half of d_out

  // converts
  int nx4 = Bq * Sq * Dq / 4;
  cvt_x<<<dim3((nx4 + 255) / 256, 2), 256, 0, stream>>>(X1, X2, (u16*)X1b, (u16*)X2b, nx4);
  cvt_bf16<<<(Dq * Uq / 4 + 255) / 256, 256, 0, stream>>>(Wq, (u16*)WqB, Dq * Uq / 4);
  transpose_cvt3<<<dim3(32, 32, 3), 256, 0, stream>>>(
      metric, (u16*)metT, Wk, (u16*)WkT, Wv, (u16*)WvT);
  bqm_kernel<<<Uq / 256, 256, 0, stream>>>(bq, metric, bqm);

  // WqmT[v][d] = sum_u metT[v][u] * WqB[d][u]   (small: keep 128^2 kernel)
  gemm_tn<1, 0><<<dim3(Uq / BM, Dq / BN, 1), 256, 0, stream>>>(
      metT, WqB, WqmT, nullptr, Uq, Uq, Dq, 0, 0, 0, Uq, 0, 0);

  const int MQ = Bq * Sq;  // 16384
  // Qb = X1b @ WqmT^T + bqm   -> d_out scratch
  gemm_tn256<1, 1><<<dim3(MQ / 256, Uq / 256, 1), 512, 0, stream>>>(
      X1b, WqmT, Qb, bqm, Dq, Dq, Uq, 0, 0, 0, Dq, 0, 0);
  // Kb = X2b @ WkT + bk       -> d_out scratch
  gemm_tn256<1, 1><<<dim3(MQ / 256, Uq / 256, 1), 512, 0, stream>>>(
      X2b, WkT, Kb, bk, Dq, Dq, Uq, 0, 0, 0, Dq, 0, 0);
  // Vt[b][u][j] = sum_d WvT[u][d] * X2b[b][j][d] + bv[u]
  gemm_tn256<1, 2><<<dim3(Uq / 256, Sq / 256, Bq), 512, 0, stream>>>(
      WvT, X2b, Vt, bv, Dq, Dq, Sq, 0, (long long)Sq * Dq, (long long)Uq * Sq, Dq, 0, 0);

  // Sc[b][i][j] = Qb_b[i] . Kb_b[j]  (bf16 out, skip fully-masked 256-tiles)
  gemm_tn256<1, 0><<<dim3(Sq / 256, Sq / 256, Bq), 512, 0, stream>>>(
      Qb, Kb, Sc, nullptr, Uq, Uq, Sq, (long long)Sq * Uq, (long long)Sq * Uq,
      (long long)Sq * Sq, Uq, 1, 0);

  softmax_causal<<<Bq * Sq, 256, 0, stream>>>(Sc);

  // Out[b][i][u] = sum_j alpha[b][i][j] * Vt[b][u][j]  (causal K-limit, longest-first)
  gemm_tn256<0, 0><<<dim3(Sq / 256, Uq / 256, Bq), 512, 0, stream>>>(
      (const bf16*)Sc, Vt, out, nullptr, Sq, Sq, Uq, (long long)Sq * Sq,
      (long long)Uq * Sq, (long long)Sq * Uq, Sq, 0, 1);

  (void)in_sizes; (void)n_in; (void)ws_size;
}